// Round 5
// baseline (1194.943 us; speedup 1.0000x reference)
//
#include <hip/hip_runtime.h>

#define D 64

typedef float f4 __attribute__((ext_vector_type(4)));

static __device__ __forceinline__ f4 fma4s(float a, f4 b, f4 c) {
  f4 r;
  r.x = fmaf(a, b.x, c.x);
  r.y = fmaf(a, b.y, c.y);
  r.z = fmaf(a, b.z, c.z);
  r.w = fmaf(a, b.w, c.w);
  return r;
}

static __device__ __forceinline__ f4 fma44(f4 a, f4 b, f4 c) {
  f4 r;
  r.x = fmaf(a.x, b.x, c.x);
  r.y = fmaf(a.y, b.y, c.y);
  r.z = fmaf(a.z, b.z, c.z);
  r.w = fmaf(a.w, b.w, c.w);
  return r;
}

static __device__ __forceinline__ f4 prelu4(f4 p, float a) {
  f4 r;
  r.x = p.x >= 0.0f ? p.x : a * p.x;
  r.y = p.y >= 0.0f ? p.y : a * p.y;
  r.z = p.z >= 0.0f ? p.z : a * p.z;
  r.w = p.w >= 0.0f ? p.w : a * p.w;
  return r;
}

// ws layout (floats): [0,4096) = U^T, [4096,8192) = V^T, [8192,8256) = c = W@s + bias
__global__ void dmc_prep(const float* __restrict__ s,
                         const float* __restrict__ U,
                         const float* __restrict__ V,
                         const float* __restrict__ W,
                         const float* __restrict__ bias,
                         float* __restrict__ ws) {
  const int t = threadIdx.x;
  float* Ut = ws;
  float* Vt = ws + D * D;
  float* c  = ws + 2 * D * D;
  for (int idx = t; idx < D * D; idx += blockDim.x) {
    const int r = idx >> 6;
    const int col = idx & (D - 1);
    Ut[col * D + r] = U[idx];
    Vt[col * D + r] = V[idx];
  }
  if (t < D) {
    float acc = bias[t];
    #pragma unroll
    for (int k = 0; k < D; ++k) acc = fmaf(W[t * D + k], s[k], acc);
    c[t] = acc;
  }
}

// One K-step group (4 k values = one f4 chunk of h/keys/s). Q is compile-time,
// so every register index is static. hres captures the thread's own h slice
// via a predicated move (no array, no re-read).
template <int Q>
static __device__ __forceinline__ void qstep(
    const f4* __restrict__ hr4, const f4* __restrict__ kr4,
    const f4* __restrict__ s4, const f4* __restrict__ Ut4,
    const f4* __restrict__ Vt4, const int slice,
    f4& acc0, f4& acc1, f4& acc2, f4& acc3, f4& hres, float& gdot) {
  const f4 hq = __builtin_nontemporal_load(&hr4[Q]);
  const f4 kq = __builtin_nontemporal_load(&kr4[Q]);
  const f4 sq = s4[Q];
  hres = (slice == (Q >> 2)) ? hq : hres;
  #pragma unroll
  for (int kk = 0; kk < 4; ++kk) {
    const float hv = hq[kk];
    const float kv = kq[kk];
    gdot = fmaf(hv + kv, sq[kk], gdot);
    const int k = 4 * Q + kk;
    const f4* __restrict__ ur = Ut4 + k * (D / 4) + slice * 4;
    const f4* __restrict__ vr = Vt4 + k * (D / 4) + slice * 4;
    acc0 = fma4s(hv, ur[0], fma4s(kv, vr[0], acc0));
    acc1 = fma4s(hv, ur[1], fma4s(kv, vr[1], acc1));
    acc2 = fma4s(hv, ur[2], fma4s(kv, vr[2], acc2));
    acc3 = fma4s(hv, ur[3], fma4s(kv, vr[3], acc3));
  }
}

// 4 threads per 64-dim row; each owns a 16-element output slice (4 f4 acc +
// 4 f4 captured h = 32 VGPR of state; no 64-float array -> nothing to spill).
// The 4 slice-threads are adjacent lanes of one wave: their identical h/keys
// requests merge in the coalescer; norm is a 4-lane shfl_xor quad reduce.
// U^T/V^T (32 KB) stay L1-hot; h/keys/out use nontemporal to not evict them.
__global__ __launch_bounds__(256, 4) void dmc_main(
    const float* __restrict__ h,
    const float* __restrict__ keys,
    const float* __restrict__ s,
    const float* __restrict__ prelu_a,
    const float* __restrict__ ws,
    float* __restrict__ out,
    const int nblocks) {
  const f4* __restrict__ Ut4 = reinterpret_cast<const f4*>(ws);
  const f4* __restrict__ Vt4 = reinterpret_cast<const f4*>(ws + D * D);
  const f4* __restrict__ c4  = reinterpret_cast<const f4*>(ws + 2 * D * D);
  const float a = prelu_a[0];

  const int tid = blockIdx.x * blockDim.x + threadIdx.x;
  const int j = tid >> 2;
  if (j >= nblocks) return;
  const int slice = tid & 3;

  const f4* __restrict__ hr4 = reinterpret_cast<const f4*>(h + (size_t)j * D);
  const f4* __restrict__ kr4 = reinterpret_cast<const f4*>(keys + (size_t)j * D);
  const f4* __restrict__ s4  = reinterpret_cast<const f4*>(s);

  f4 acc0 = c4[slice * 4 + 0];
  f4 acc1 = c4[slice * 4 + 1];
  f4 acc2 = c4[slice * 4 + 2];
  f4 acc3 = c4[slice * 4 + 3];
  f4 hres0 = {0.f, 0.f, 0.f, 0.f};
  f4 hres1 = hres0, hres2 = hres0, hres3 = hres0;
  float gdot = 0.0f;

  qstep<0>(hr4, kr4, s4, Ut4, Vt4, slice, acc0, acc1, acc2, acc3, hres0, gdot);
  qstep<1>(hr4, kr4, s4, Ut4, Vt4, slice, acc0, acc1, acc2, acc3, hres1, gdot);
  qstep<2>(hr4, kr4, s4, Ut4, Vt4, slice, acc0, acc1, acc2, acc3, hres2, gdot);
  qstep<3>(hr4, kr4, s4, Ut4, Vt4, slice, acc0, acc1, acc2, acc3, hres3, gdot);
  qstep<4>(hr4, kr4, s4, Ut4, Vt4, slice, acc0, acc1, acc2, acc3, hres0, gdot);
  qstep<5>(hr4, kr4, s4, Ut4, Vt4, slice, acc0, acc1, acc2, acc3, hres1, gdot);
  qstep<6>(hr4, kr4, s4, Ut4, Vt4, slice, acc0, acc1, acc2, acc3, hres2, gdot);
  qstep<7>(hr4, kr4, s4, Ut4, Vt4, slice, acc0, acc1, acc2, acc3, hres3, gdot);
  qstep<8>(hr4, kr4, s4, Ut4, Vt4, slice, acc0, acc1, acc2, acc3, hres0, gdot);
  qstep<9>(hr4, kr4, s4, Ut4, Vt4, slice, acc0, acc1, acc2, acc3, hres1, gdot);
  qstep<10>(hr4, kr4, s4, Ut4, Vt4, slice, acc0, acc1, acc2, acc3, hres2, gdot);
  qstep<11>(hr4, kr4, s4, Ut4, Vt4, slice, acc0, acc1, acc2, acc3, hres3, gdot);
  qstep<12>(hr4, kr4, s4, Ut4, Vt4, slice, acc0, acc1, acc2, acc3, hres0, gdot);
  qstep<13>(hr4, kr4, s4, Ut4, Vt4, slice, acc0, acc1, acc2, acc3, hres1, gdot);
  qstep<14>(hr4, kr4, s4, Ut4, Vt4, slice, acc0, acc1, acc2, acc3, hres2, gdot);
  qstep<15>(hr4, kr4, s4, Ut4, Vt4, slice, acc0, acc1, acc2, acc3, hres3, gdot);

  const float g = 1.0f / (1.0f + __expf(-gdot));

  f4 o0 = fma4s(g, prelu4(acc0, a), hres0);
  f4 o1 = fma4s(g, prelu4(acc1, a), hres1);
  f4 o2 = fma4s(g, prelu4(acc2, a), hres2);
  f4 o3 = fma4s(g, prelu4(acc3, a), hres3);

  f4 sv = o0 * o0;
  sv = fma44(o1, o1, sv);
  sv = fma44(o2, o2, sv);
  sv = fma44(o3, o3, sv);
  float ss = sv.x + sv.y + sv.z + sv.w;
  ss += __shfl_xor(ss, 1);
  ss += __shfl_xor(ss, 2);
  const float rn = rsqrtf(ss);

  f4* __restrict__ orow4 = reinterpret_cast<f4*>(out + (size_t)j * D) + slice * 4;
  o0 *= rn; o1 *= rn; o2 *= rn; o3 *= rn;
  __builtin_nontemporal_store(o0, &orow4[0]);
  __builtin_nontemporal_store(o1, &orow4[1]);
  __builtin_nontemporal_store(o2, &orow4[2]);
  __builtin_nontemporal_store(o3, &orow4[3]);
}

extern "C" void kernel_launch(void* const* d_in, const int* in_sizes, int n_in,
                              void* d_out, int out_size, void* d_ws, size_t ws_size,
                              hipStream_t stream) {
  const float* s       = (const float*)d_in[0];
  const float* h       = (const float*)d_in[1];
  const float* keys    = (const float*)d_in[2];
  const float* U       = (const float*)d_in[3];
  const float* V       = (const float*)d_in[4];
  const float* W       = (const float*)d_in[5];
  const float* bias    = (const float*)d_in[6];
  const float* prelu_a = (const float*)d_in[7];
  float* out = (float*)d_out;
  float* ws  = (float*)d_ws;

  const int nblocks = in_sizes[1] / D;

  dmc_prep<<<1, 256, 0, stream>>>(s, U, V, W, bias, ws);
  const long long total_threads = 4LL * nblocks;
  const int grid = (int)((total_threads + 255) / 256);
  dmc_main<<<grid, 256, 0, stream>>>(h, keys, s, prelu_a, ws, out, nblocks);
}

// Round 6
// 1045.551 us; speedup vs baseline: 1.1429x; 1.1429x over previous
//
#include <hip/hip_runtime.h>

#define D 64

typedef float f4 __attribute__((ext_vector_type(4)));

static __device__ __forceinline__ f4 fma4s(float a, f4 b, f4 c) {
  f4 r;
  r.x = fmaf(a, b.x, c.x);
  r.y = fmaf(a, b.y, c.y);
  r.z = fmaf(a, b.z, c.z);
  r.w = fmaf(a, b.w, c.w);
  return r;
}

static __device__ __forceinline__ f4 fma44(f4 a, f4 b, f4 c) {
  f4 r;
  r.x = fmaf(a.x, b.x, c.x);
  r.y = fmaf(a.y, b.y, c.y);
  r.z = fmaf(a.z, b.z, c.z);
  r.w = fmaf(a.w, b.w, c.w);
  return r;
}

static __device__ __forceinline__ f4 prelu4(f4 p, float a) {
  f4 r;
  r.x = p.x >= 0.0f ? p.x : a * p.x;
  r.y = p.y >= 0.0f ? p.y : a * p.y;
  r.z = p.z >= 0.0f ? p.z : a * p.z;
  r.w = p.w >= 0.0f ? p.w : a * p.w;
  return r;
}

// ws layout (floats): [0,4096) = U^T, [4096,8192) = V^T, [8192,8256) = c = W@s + bias
__global__ void dmc_prep(const float* __restrict__ s,
                         const float* __restrict__ U,
                         const float* __restrict__ V,
                         const float* __restrict__ W,
                         const float* __restrict__ bias,
                         float* __restrict__ ws) {
  const int t = threadIdx.x;
  float* Ut = ws;
  float* Vt = ws + D * D;
  float* c  = ws + 2 * D * D;
  for (int idx = t; idx < D * D; idx += blockDim.x) {
    const int r = idx >> 6;
    const int col = idx & (D - 1);
    Ut[col * D + r] = U[idx];
    Vt[col * D + r] = V[idx];
  }
  if (t < D) {
    float acc = bias[t];
    #pragma unroll
    for (int k = 0; k < D; ++k) acc = fmaf(W[t * D + k], s[k], acc);
    c[t] = acc;
  }
}

// One K-step group (4 k values = one f4 chunk of h/keys/s). Q is compile-time,
// so every register index is static. hres captures the thread's own h slice
// via a predicated move (no array, no re-read).
// NOTE: all loads/stores are CACHED (no nontemporal) — R5 showed nt bypasses
// L2's partial-line merging and amplifies this kernel's 16B-per-64B-sector
// access pattern ~4x at HBM (FETCH 1.15GB / WRITE 726MB vs 256/128 ideal).
template <int Q>
static __device__ __forceinline__ void qstep(
    const f4* __restrict__ hr4, const f4* __restrict__ kr4,
    const f4* __restrict__ s4, const f4* __restrict__ Ut4,
    const f4* __restrict__ Vt4, const int slice,
    f4& acc0, f4& acc1, f4& acc2, f4& acc3, f4& hres, float& gdot) {
  const f4 hq = hr4[Q];
  const f4 kq = kr4[Q];
  const f4 sq = s4[Q];
  hres = (slice == (Q >> 2)) ? hq : hres;
  #pragma unroll
  for (int kk = 0; kk < 4; ++kk) {
    const float hv = hq[kk];
    const float kv = kq[kk];
    gdot = fmaf(hv + kv, sq[kk], gdot);
    const int k = 4 * Q + kk;
    const f4* __restrict__ ur = Ut4 + k * (D / 4) + slice * 4;
    const f4* __restrict__ vr = Vt4 + k * (D / 4) + slice * 4;
    acc0 = fma4s(hv, ur[0], fma4s(kv, vr[0], acc0));
    acc1 = fma4s(hv, ur[1], fma4s(kv, vr[1], acc1));
    acc2 = fma4s(hv, ur[2], fma4s(kv, vr[2], acc2));
    acc3 = fma4s(hv, ur[3], fma4s(kv, vr[3], acc3));
  }
}

// 4 threads per 64-dim row; each owns a 16-element output slice (4 f4 acc +
// 4 f4 captured h = 32 VGPR of state; no 64-float array -> nothing to spill).
// The 4 slice-threads are adjacent lanes of one wave; norm is a 4-lane
// shfl_xor quad reduce. U^T/V^T (32 KB) stay L1/L2-hot.
__global__ __launch_bounds__(256, 4) void dmc_main(
    const float* __restrict__ h,
    const float* __restrict__ keys,
    const float* __restrict__ s,
    const float* __restrict__ prelu_a,
    const float* __restrict__ ws,
    float* __restrict__ out,
    const int nblocks) {
  const f4* __restrict__ Ut4 = reinterpret_cast<const f4*>(ws);
  const f4* __restrict__ Vt4 = reinterpret_cast<const f4*>(ws + D * D);
  const f4* __restrict__ c4  = reinterpret_cast<const f4*>(ws + 2 * D * D);
  const float a = prelu_a[0];

  const int tid = blockIdx.x * blockDim.x + threadIdx.x;
  const int j = tid >> 2;
  if (j >= nblocks) return;
  const int slice = tid & 3;

  const f4* __restrict__ hr4 = reinterpret_cast<const f4*>(h + (size_t)j * D);
  const f4* __restrict__ kr4 = reinterpret_cast<const f4*>(keys + (size_t)j * D);
  const f4* __restrict__ s4  = reinterpret_cast<const f4*>(s);

  f4 acc0 = c4[slice * 4 + 0];
  f4 acc1 = c4[slice * 4 + 1];
  f4 acc2 = c4[slice * 4 + 2];
  f4 acc3 = c4[slice * 4 + 3];
  f4 hres0 = {0.f, 0.f, 0.f, 0.f};
  f4 hres1 = hres0, hres2 = hres0, hres3 = hres0;
  float gdot = 0.0f;

  qstep<0>(hr4, kr4, s4, Ut4, Vt4, slice, acc0, acc1, acc2, acc3, hres0, gdot);
  qstep<1>(hr4, kr4, s4, Ut4, Vt4, slice, acc0, acc1, acc2, acc3, hres1, gdot);
  qstep<2>(hr4, kr4, s4, Ut4, Vt4, slice, acc0, acc1, acc2, acc3, hres2, gdot);
  qstep<3>(hr4, kr4, s4, Ut4, Vt4, slice, acc0, acc1, acc2, acc3, hres3, gdot);
  qstep<4>(hr4, kr4, s4, Ut4, Vt4, slice, acc0, acc1, acc2, acc3, hres0, gdot);
  qstep<5>(hr4, kr4, s4, Ut4, Vt4, slice, acc0, acc1, acc2, acc3, hres1, gdot);
  qstep<6>(hr4, kr4, s4, Ut4, Vt4, slice, acc0, acc1, acc2, acc3, hres2, gdot);
  qstep<7>(hr4, kr4, s4, Ut4, Vt4, slice, acc0, acc1, acc2, acc3, hres3, gdot);
  qstep<8>(hr4, kr4, s4, Ut4, Vt4, slice, acc0, acc1, acc2, acc3, hres0, gdot);
  qstep<9>(hr4, kr4, s4, Ut4, Vt4, slice, acc0, acc1, acc2, acc3, hres1, gdot);
  qstep<10>(hr4, kr4, s4, Ut4, Vt4, slice, acc0, acc1, acc2, acc3, hres2, gdot);
  qstep<11>(hr4, kr4, s4, Ut4, Vt4, slice, acc0, acc1, acc2, acc3, hres3, gdot);
  qstep<12>(hr4, kr4, s4, Ut4, Vt4, slice, acc0, acc1, acc2, acc3, hres0, gdot);
  qstep<13>(hr4, kr4, s4, Ut4, Vt4, slice, acc0, acc1, acc2, acc3, hres1, gdot);
  qstep<14>(hr4, kr4, s4, Ut4, Vt4, slice, acc0, acc1, acc2, acc3, hres2, gdot);
  qstep<15>(hr4, kr4, s4, Ut4, Vt4, slice, acc0, acc1, acc2, acc3, hres3, gdot);

  const float g = 1.0f / (1.0f + __expf(-gdot));

  f4 o0 = fma4s(g, prelu4(acc0, a), hres0);
  f4 o1 = fma4s(g, prelu4(acc1, a), hres1);
  f4 o2 = fma4s(g, prelu4(acc2, a), hres2);
  f4 o3 = fma4s(g, prelu4(acc3, a), hres3);

  f4 sv = o0 * o0;
  sv = fma44(o1, o1, sv);
  sv = fma44(o2, o2, sv);
  sv = fma44(o3, o3, sv);
  float ss = sv.x + sv.y + sv.z + sv.w;
  ss += __shfl_xor(ss, 1);
  ss += __shfl_xor(ss, 2);
  const float rn = rsqrtf(ss);

  f4* __restrict__ orow4 = reinterpret_cast<f4*>(out + (size_t)j * D) + slice * 4;
  o0 *= rn; o1 *= rn; o2 *= rn; o3 *= rn;
  orow4[0] = o0;
  orow4[1] = o1;
  orow4[2] = o2;
  orow4[3] = o3;
}

extern "C" void kernel_launch(void* const* d_in, const int* in_sizes, int n_in,
                              void* d_out, int out_size, void* d_ws, size_t ws_size,
                              hipStream_t stream) {
  const float* s       = (const float*)d_in[0];
  const float* h       = (const float*)d_in[1];
  const float* keys    = (const float*)d_in[2];
  const float* U       = (const float*)d_in[3];
  const float* V       = (const float*)d_in[4];
  const float* W       = (const float*)d_in[5];
  const float* bias    = (const float*)d_in[6];
  const float* prelu_a = (const float*)d_in[7];
  float* out = (float*)d_out;
  float* ws  = (float*)d_ws;

  const int nblocks = in_sizes[1] / D;

  dmc_prep<<<1, 256, 0, stream>>>(s, U, V, W, bias, ws);
  const long long total_threads = 4LL * nblocks;
  const int grid = (int)((total_threads + 255) / 256);
  dmc_main<<<grid, 256, 0, stream>>>(h, keys, s, prelu_a, ws, out, nblocks);
}

// Round 8
// 279.255 us; speedup vs baseline: 4.2790x; 3.7441x over previous
//
#include <hip/hip_runtime.h>

#define D 64
#define ROWS 64
#define TPB 256

typedef float f4 __attribute__((ext_vector_type(4)));

static __device__ __forceinline__ f4 fma4s(float a, f4 b, f4 c) {
  f4 r;
  r.x = fmaf(a, b.x, c.x);
  r.y = fmaf(a, b.y, c.y);
  r.z = fmaf(a, b.z, c.z);
  r.w = fmaf(a, b.w, c.w);
  return r;
}

static __device__ __forceinline__ f4 prelu4(f4 p, float a) {
  f4 r;
  r.x = p.x >= 0.0f ? p.x : a * p.x;
  r.y = p.y >= 0.0f ? p.y : a * p.y;
  r.z = p.z >= 0.0f ? p.z : a * p.z;
  r.w = p.w >= 0.0f ? p.w : a * p.w;
  return r;
}

// Fully self-contained single kernel (R7's prep->main ws dependency caused
// post-timing divergence under graph replay; no workspace, no cross-kernel
// state). Block = 256 threads (4 waves) owns a 64-row tile:
//   wave w computes cols [w*16, w*16+16) for all 64 rows; lane = row.
// U/V are read DIRECTLY row-major: U[c][4q..+3] is contiguous and
// wave-uniform -> s_load_dwordx4 broadcast; inner loop is v_fma(vgpr_h,
// sgpr_u, acc) with 64 rows of useful work per instruction (the R1-R6
// per-lane-VMEM U/V re-read was the structural bottleneck). h/keys staged
// coalesced into LDS with XOR chunk swizzle (phys = q ^ (r&15)) so per-row
// ds_read_b128 is conflict-free. c = W@s + bias recomputed per block (W is
// L2-hot, 64 threads, trivial). Cross-wave norm via LDS partials.
__global__ __launch_bounds__(TPB, 4) void dmc_fused(
    const float* __restrict__ h,
    const float* __restrict__ keys,
    const float* __restrict__ s,
    const float* __restrict__ U,
    const float* __restrict__ V,
    const float* __restrict__ W,
    const float* __restrict__ bias,
    const float* __restrict__ prelu_a,
    float* __restrict__ out,
    const int nblocks) {
  __shared__ __align__(16) float hT[ROWS * D];
  __shared__ __align__(16) float kT[ROWS * D];
  __shared__ __align__(16) float cc[D];
  __shared__ float ssb[4 * ROWS];

  const int tid  = threadIdx.x;
  const int lane = tid & 63;
  const int wv   = __builtin_amdgcn_readfirstlane(tid >> 6);  // 0..3, uniform
  const int j0   = blockIdx.x * ROWS;
  const int nrem = nblocks - j0;  // rows in this tile (may exceed 64)

  // ---- stage h and keys tiles, coalesced, zero-filling OOB rows ----
  const f4* __restrict__ hg = reinterpret_cast<const f4*>(h + (size_t)j0 * D);
  const f4* __restrict__ kg = reinterpret_cast<const f4*>(keys + (size_t)j0 * D);
  f4* __restrict__ hTw = reinterpret_cast<f4*>(hT);
  f4* __restrict__ kTw = reinterpret_cast<f4*>(kT);
  #pragma unroll
  for (int t = 0; t < 4; ++t) {
    const int gi = tid + TPB * t;      // f4 index 0..1023
    const int r  = gi >> 4;
    const int ch = gi & 15;
    f4 v = {0.f, 0.f, 0.f, 0.f};
    if (r < nrem) v = hg[gi];
    hTw[r * 16 + (ch ^ (r & 15))] = v;
  }
  #pragma unroll
  for (int t = 0; t < 4; ++t) {
    const int gi = tid + TPB * t;
    const int r  = gi >> 4;
    const int ch = gi & 15;
    f4 v = {0.f, 0.f, 0.f, 0.f};
    if (r < nrem) v = kg[gi];
    kTw[r * 16 + (ch ^ (r & 15))] = v;
  }

  // ---- cc[c] = bias[c] + W[c,:] @ s  (64 threads, W is L2-hot) ----
  if (tid < D) {
    const f4* __restrict__ wr = reinterpret_cast<const f4*>(W + tid * D);
    const f4* __restrict__ sr = reinterpret_cast<const f4*>(s);
    float acc = bias[tid];
    #pragma unroll
    for (int q = 0; q < 16; ++q) {
      const f4 wq = wr[q];
      const f4 sq = sr[q];
      acc = fmaf(wq.x, sq.x, acc);
      acc = fmaf(wq.y, sq.y, acc);
      acc = fmaf(wq.z, sq.z, acc);
      acc = fmaf(wq.w, sq.w, acc);
    }
    cc[tid] = acc;
  }
  __syncthreads();

  // ---- per-lane compute: row = lane, cols [wv*16, wv*16+16) ----
  const int c0 = wv << 4;
  const f4* __restrict__ ccv = reinterpret_cast<const f4*>(cc + c0);
  f4 acc0 = ccv[0];
  f4 acc1 = ccv[1];
  f4 acc2 = ccv[2];
  f4 acc3 = ccv[3];

  const f4* __restrict__ U4  = reinterpret_cast<const f4*>(U);
  const f4* __restrict__ V4  = reinterpret_cast<const f4*>(V);
  const f4* __restrict__ sg4 = reinterpret_cast<const f4*>(s);
  const f4* __restrict__ hT4 = reinterpret_cast<const f4*>(hT);
  const f4* __restrict__ kT4 = reinterpret_cast<const f4*>(kT);
  const int rbase = lane * 16;
  const int rsw   = lane & 15;
  float gd = 0.0f;

  #pragma unroll 2
  for (int q = 0; q < 16; ++q) {
    const f4 h4 = hT4[rbase + (q ^ rsw)];
    const f4 k4 = kT4[rbase + (q ^ rsw)];
    const f4 sq = sg4[q];
    gd = fmaf(h4.x + k4.x, sq.x, gd);
    gd = fmaf(h4.y + k4.y, sq.y, gd);
    gd = fmaf(h4.z + k4.z, sq.z, gd);
    gd = fmaf(h4.w + k4.w, sq.w, gd);
#define COL1(g, CMP, cidx) { \
    const f4 u  = U4[(c0 + 4 * (g) + (cidx)) * 16 + q]; \
    const f4 vv = V4[(c0 + 4 * (g) + (cidx)) * 16 + q]; \
    float t = acc##g.CMP; \
    t = fmaf(h4.x, u.x, t);  t = fmaf(h4.y, u.y, t); \
    t = fmaf(h4.z, u.z, t);  t = fmaf(h4.w, u.w, t); \
    t = fmaf(k4.x, vv.x, t); t = fmaf(k4.y, vv.y, t); \
    t = fmaf(k4.z, vv.z, t); t = fmaf(k4.w, vv.w, t); \
    acc##g.CMP = t; }
#define COLG(g) COL1(g, x, 0) COL1(g, y, 1) COL1(g, z, 2) COL1(g, w, 3)
    COLG(0) COLG(1) COLG(2) COLG(3)
#undef COLG
#undef COL1
  }

  const float gt = 1.0f / (1.0f + __expf(-gd));
  const float a  = prelu_a[0];

  // gated residual (h re-read from LDS) + partial sum of squares
  float ss = 0.0f;
  const int chbase = wv << 2;  // logical chunk of this wave's col range
#define EPI(n) { const f4 hh = hT4[rbase + ((chbase + n) ^ rsw)]; \
  acc##n = fma4s(gt, prelu4(acc##n, a), hh); \
  ss = fmaf(acc##n.x, acc##n.x, ss); ss = fmaf(acc##n.y, acc##n.y, ss); \
  ss = fmaf(acc##n.z, acc##n.z, ss); ss = fmaf(acc##n.w, acc##n.w, ss); }
  EPI(0) EPI(1) EPI(2) EPI(3)
#undef EPI

  // cross-wave norm exchange
  ssb[(wv << 6) + lane] = ss;
  __syncthreads();
  const float rn =
      rsqrtf(ssb[lane] + ssb[64 + lane] + ssb[128 + lane] + ssb[192 + lane]);

  if (lane < nrem) {
    f4* __restrict__ orow =
        reinterpret_cast<f4*>(out + (size_t)(j0 + lane) * D + c0);
    orow[0] = acc0 * rn;
    orow[1] = acc1 * rn;
    orow[2] = acc2 * rn;
    orow[3] = acc3 * rn;
  }
}

extern "C" void kernel_launch(void* const* d_in, const int* in_sizes, int n_in,
                              void* d_out, int out_size, void* d_ws, size_t ws_size,
                              hipStream_t stream) {
  const float* s       = (const float*)d_in[0];
  const float* h       = (const float*)d_in[1];
  const float* keys    = (const float*)d_in[2];
  const float* U       = (const float*)d_in[3];
  const float* V       = (const float*)d_in[4];
  const float* W       = (const float*)d_in[5];
  const float* bias    = (const float*)d_in[6];
  const float* prelu_a = (const float*)d_in[7];
  float* out = (float*)d_out;

  const int nblocks = in_sizes[1] / D;
  const int grid = (nblocks + ROWS - 1) / ROWS;
  dmc_fused<<<grid, TPB, 0, stream>>>(h, keys, s, U, V, W, bias, prelu_a, out,
                                      nblocks);
}

// Round 9
// 110.804 us; speedup vs baseline: 10.7843x; 2.5203x over previous
//
#include <hip/hip_runtime.h>

#define D 64
#define ROWS 64
#define TPB 256

typedef float f4 __attribute__((ext_vector_type(4)));
typedef short s8 __attribute__((ext_vector_type(8)));

static __device__ __forceinline__ unsigned short f2bf(float x) {
  union { float f; unsigned u; } v; v.f = x;
  return (unsigned short)((v.u + 0x7FFFu + ((v.u >> 16) & 1u)) >> 16);
}

static __device__ __forceinline__ s8 pack8(f4 a, f4 b) {
  s8 r;
  r[0] = (short)f2bf(a.x); r[1] = (short)f2bf(a.y);
  r[2] = (short)f2bf(a.z); r[3] = (short)f2bf(a.w);
  r[4] = (short)f2bf(b.x); r[5] = (short)f2bf(b.y);
  r[6] = (short)f2bf(b.z); r[7] = (short)f2bf(b.w);
  return r;
}

static __device__ __forceinline__ f4 fma4s(float a, f4 b, f4 c) {
  f4 r;
  r.x = fmaf(a, b.x, c.x);
  r.y = fmaf(a, b.y, c.y);
  r.z = fmaf(a, b.z, c.z);
  r.w = fmaf(a, b.w, c.w);
  return r;
}

static __device__ __forceinline__ f4 prelu4(f4 p, float a) {
  f4 r;
  r.x = p.x >= 0.0f ? p.x : a * p.x;
  r.y = p.y >= 0.0f ? p.y : a * p.y;
  r.z = p.z >= 0.0f ? p.z : a * p.z;
  r.w = p.w >= 0.0f ? p.w : a * p.w;
  return r;
}

// Single self-contained kernel (R7 lesson). Block = 256 threads (4 waves)
// owns a 64-row tile. The two matvecs (hb@U^T + keys@V^T) run on the MATRIX
// pipe via mfma_f32_16x16x32_bf16 (R8 showed MfmaUtil=0, VALU-issue-bound at
// 3.5x the FMA floor). Wave wv owns batch rows [wv*16, wv*16+16) as the MFMA
// B-operand (B[k][n] = hb[n][k], lane n = l&15, k = 8*(l>>4)+j, built from
// swizzled f32 LDS + RNE cvt). U/V are converted once per block to bf16 LDS
// [c][k] row-major with 16B-chunk XOR swizzle -> conflict-free A-fragments
// (A[m][k] = U[cb*16+m][k], one ds_read_b128 each). D layout (m89-verified):
// lane holds D[m=4*(l>>4)+reg][n=l&15] -> n = batch row, m = output col.
// Gate, residual (f32 h), norm stay fp32; only U*h+V*k is bf16.
__global__ __launch_bounds__(TPB, 2) void dmc_fused(
    const float* __restrict__ h,
    const float* __restrict__ keys,
    const float* __restrict__ s,
    const float* __restrict__ U,
    const float* __restrict__ V,
    const float* __restrict__ W,
    const float* __restrict__ bias,
    const float* __restrict__ prelu_a,
    float* __restrict__ out,
    const int nblocks) {
  __shared__ __align__(16) float hT[ROWS * D];            // 16KB f32, swizzled
  __shared__ __align__(16) float kT[ROWS * D];            // 16KB
  __shared__ __align__(16) unsigned short Ub[D * D];      // 8KB bf16, swizzled
  __shared__ __align__(16) unsigned short Vb[D * D];      // 8KB
  __shared__ __align__(16) float cc[D];

  const int tid  = threadIdx.x;
  const int lane = tid & 63;
  const int wv   = tid >> 6;            // 0..3 = batch row-block
  const int j0   = blockIdx.x * ROWS;
  const int nrem = nblocks - j0;

  // ---- stage h, keys (coalesced f4, chunk-XOR swizzle, zero-fill OOB) ----
  const f4* __restrict__ hg = reinterpret_cast<const f4*>(h + (size_t)j0 * D);
  const f4* __restrict__ kg = reinterpret_cast<const f4*>(keys + (size_t)j0 * D);
  f4* __restrict__ hTw = reinterpret_cast<f4*>(hT);
  f4* __restrict__ kTw = reinterpret_cast<f4*>(kT);
  #pragma unroll
  for (int t = 0; t < 4; ++t) {
    const int gi = tid + TPB * t;       // f4 index 0..1023
    const int r  = gi >> 4;
    const int ch = gi & 15;
    f4 v = {0.f, 0.f, 0.f, 0.f};
    if (r < nrem) v = hg[gi];
    hTw[r * 16 + (ch ^ (r & 15))] = v;
  }
  #pragma unroll
  for (int t = 0; t < 4; ++t) {
    const int gi = tid + TPB * t;
    const int r  = gi >> 4;
    const int ch = gi & 15;
    f4 v = {0.f, 0.f, 0.f, 0.f};
    if (r < nrem) v = kg[gi];
    kTw[r * 16 + (ch ^ (r & 15))] = v;
  }

  // ---- stage U, V -> bf16 LDS [c][64k], 16B chunk sl with phys = sl^(c&7) ----
  const f4* __restrict__ Ug = reinterpret_cast<const f4*>(U);
  const f4* __restrict__ Vg = reinterpret_cast<const f4*>(V);
  s8* __restrict__ Ub8w = reinterpret_cast<s8*>(Ub);
  s8* __restrict__ Vb8w = reinterpret_cast<s8*>(Vb);
  #pragma unroll
  for (int t = 0; t < 2; ++t) {
    const int m  = tid + TPB * t;       // 0..511 chunk id
    const int c  = m >> 3;
    const int sl = m & 7;
    Ub8w[c * 8 + (sl ^ (c & 7))] = pack8(Ug[c * 16 + sl * 2], Ug[c * 16 + sl * 2 + 1]);
    Vb8w[c * 8 + (sl ^ (c & 7))] = pack8(Vg[c * 16 + sl * 2], Vg[c * 16 + sl * 2 + 1]);
  }

  // ---- cc[c] = bias[c] + W[c,:] @ s ----
  if (tid < D) {
    const f4* __restrict__ wr = reinterpret_cast<const f4*>(W + tid * D);
    const f4* __restrict__ sr = reinterpret_cast<const f4*>(s);
    float acc = bias[tid];
    #pragma unroll
    for (int q = 0; q < 16; ++q) {
      const f4 wq = wr[q];
      const f4 sq = sr[q];
      acc = fmaf(wq.x, sq.x, acc);
      acc = fmaf(wq.y, sq.y, acc);
      acc = fmaf(wq.z, sq.z, acc);
      acc = fmaf(wq.w, sq.w, acc);
    }
    cc[tid] = acc;
  }
  __syncthreads();

  // ---- per-lane geometry ----
  const int g  = lane >> 4;             // 0..3 (k-group / col-subgroup)
  const int rl = lane & 15;             // MFMA n / m index
  const int r  = wv * 16 + rl;          // this lane's batch row in tile
  const int rbase = r * 16;
  const int rsw   = r & 15;
  const f4* __restrict__ hT4 = reinterpret_cast<const f4*>(hT);
  const f4* __restrict__ kT4 = reinterpret_cast<const f4*>(kT);
  const s8* __restrict__ Ub8 = reinterpret_cast<const s8*>(Ub);
  const s8* __restrict__ Vb8 = reinterpret_cast<const s8*>(Vb);
  const f4* __restrict__ cc4 = reinterpret_cast<const f4*>(cc);

  // acc_cb[reg] = pre[row r][col cb*16 + 4g + reg]
  f4 acc0 = cc4[0 + g];
  f4 acc1 = cc4[4 + g];
  f4 acc2 = cc4[8 + g];
  f4 acc3 = cc4[12 + g];

  // ---- MFMA main: K=64 as 2 slices of 32 ----
  #pragma unroll
  for (int ks = 0; ks < 2; ++ks) {
    const int q0 = ks * 8 + g * 2;      // lane's f32 chunk pair for k=8*(l>>4)+j
    const f4 h0 = hT4[rbase + (q0 ^ rsw)];
    const f4 h1 = hT4[rbase + ((q0 + 1) ^ rsw)];
    const f4 k0 = kT4[rbase + (q0 ^ rsw)];
    const f4 k1 = kT4[rbase + ((q0 + 1) ^ rsw)];
    const s8 bh = pack8(h0, h1);
    const s8 bk = pack8(k0, k1);
    const int asl = ks * 4 + g;         // 16B slot within a U/V row
#define CBSTEP(cb, ACC) { \
    const int c = (cb) * 16 + rl; \
    const s8 au = Ub8[c * 8 + (asl ^ (c & 7))]; \
    const s8 av = Vb8[c * 8 + (asl ^ (c & 7))]; \
    ACC = __builtin_amdgcn_mfma_f32_16x16x32_bf16(au, bh, ACC, 0, 0, 0); \
    ACC = __builtin_amdgcn_mfma_f32_16x16x32_bf16(av, bk, ACC, 0, 0, 0); }
    CBSTEP(0, acc0)
    CBSTEP(1, acc1)
    CBSTEP(2, acc2)
    CBSTEP(3, acc3)
#undef CBSTEP
  }

  // ---- gate: gd = <s, h_r + k_r>, 4 lanes per row, f32 ----
  float gd = 0.0f;
  const f4* __restrict__ sg4 = reinterpret_cast<const f4*>(s);
  #pragma unroll
  for (int i = 0; i < 4; ++i) {
    const int q = g * 4 + i;
    const f4 hv = hT4[rbase + (q ^ rsw)];
    const f4 kv = kT4[rbase + (q ^ rsw)];
    const f4 sv = sg4[q];
    gd = fmaf(hv.x + kv.x, sv.x, gd);
    gd = fmaf(hv.y + kv.y, sv.y, gd);
    gd = fmaf(hv.z + kv.z, sv.z, gd);
    gd = fmaf(hv.w + kv.w, sv.w, gd);
  }
  gd += __shfl_xor(gd, 16);
  gd += __shfl_xor(gd, 32);
  const float gt = 1.0f / (1.0f + __expf(-gd));
  const float a  = prelu_a[0];

  // ---- gated residual (f32 h from LDS) + row norm ----
  const f4 hr0 = hT4[rbase + ((0 + g) ^ rsw)];
  const f4 hr1 = hT4[rbase + ((4 + g) ^ rsw)];
  const f4 hr2 = hT4[rbase + ((8 + g) ^ rsw)];
  const f4 hr3 = hT4[rbase + ((12 + g) ^ rsw)];
  f4 o0 = fma4s(gt, prelu4(acc0, a), hr0);
  f4 o1 = fma4s(gt, prelu4(acc1, a), hr1);
  f4 o2 = fma4s(gt, prelu4(acc2, a), hr2);
  f4 o3 = fma4s(gt, prelu4(acc3, a), hr3);

  float ss = o0.x * o0.x + o0.y * o0.y + o0.z * o0.z + o0.w * o0.w;
  ss = fmaf(o1.x, o1.x, ss); ss = fmaf(o1.y, o1.y, ss);
  ss = fmaf(o1.z, o1.z, ss); ss = fmaf(o1.w, o1.w, ss);
  ss = fmaf(o2.x, o2.x, ss); ss = fmaf(o2.y, o2.y, ss);
  ss = fmaf(o2.z, o2.z, ss); ss = fmaf(o2.w, o2.w, ss);
  ss = fmaf(o3.x, o3.x, ss); ss = fmaf(o3.y, o3.y, ss);
  ss = fmaf(o3.z, o3.z, ss); ss = fmaf(o3.w, o3.w, ss);
  ss += __shfl_xor(ss, 16);
  ss += __shfl_xor(ss, 32);
  const float rn = rsqrtf(ss);

  if (r < nrem) {
    float* __restrict__ orow = out + (size_t)(j0 + r) * D + g * 4;
    *reinterpret_cast<f4*>(orow +  0) = o0 * rn;
    *reinterpret_cast<f4*>(orow + 16) = o1 * rn;
    *reinterpret_cast<f4*>(orow + 32) = o2 * rn;
    *reinterpret_cast<f4*>(orow + 48) = o3 * rn;
  }
}

extern "C" void kernel_launch(void* const* d_in, const int* in_sizes, int n_in,
                              void* d_out, int out_size, void* d_ws, size_t ws_size,
                              hipStream_t stream) {
  const float* s       = (const float*)d_in[0];
  const float* h       = (const float*)d_in[1];
  const float* keys    = (const float*)d_in[2];
  const float* U       = (const float*)d_in[3];
  const float* V       = (const float*)d_in[4];
  const float* W       = (const float*)d_in[5];
  const float* bias    = (const float*)d_in[6];
  const float* prelu_a = (const float*)d_in[7];
  float* out = (float*)d_out;

  const int nblocks = in_sizes[1] / D;
  const int grid = (nblocks + ROWS - 1) / ROWS;
  dmc_fused<<<grid, TPB, 0, stream>>>(h, keys, s, U, V, W, bias, prelu_a, out,
                                      nblocks);
}